// Round 3
// baseline (3669.693 us; speedup 1.0000x reference)
//
#include <hip/hip_runtime.h>
#include <cstddef>

// ---------------------------------------------------------------------------
// MT_RNN round 8: single mega-kernel — recurrence on 16 CUs overlapped with
// producer/consumer GEMM chains on the other 240 CUs.
//
// Evidence: rnn_serial is pinned at ~2300 cyc/step across three structural
// variants (r5/r6/r7: 128/32/64 LDS reads per step) -> the barrier-locked
// serial chain is the floor for this decomposition. Meanwhile 240 CUs idle
// for 989 us and the GEMM chain (~470 us) serializes around it.
//
// New structure (one launch, 256 blocks x 512 thr):
//   blocks 0-15 : round-7 rnn loop + zx-flag polling + h-progress publish
//   blocks 16+  : phase A: fused (1)+(2)+(3) per 32-row tile -> zx + flag
//                 phase B: fused (5)+(6)+(7) per tile, gated on rnn progress
// Sync: device-scope release/acquire atomics on __device__ flags; prep kernel
// zeroes flags and pre-converts all weights to fp16 device globals.
// Deadlock-free by residency: 256 blocks x 8 waves x 33KB LDS all co-resident;
// wait graph acyclic (rnn <- phaseA, phaseB <- rnn).
// Buffers: bufA = zx [T,B,H] fp16 (phase A writes, rnn reads);
//          bufB = h_all [T,B,H] fp16 (rnn writes, phase B reads).
// ---------------------------------------------------------------------------

typedef _Float16 halfx8 __attribute__((ext_vector_type(8)));
typedef _Float16 halfx4 __attribute__((ext_vector_type(4)));
typedef float    f32x4  __attribute__((ext_vector_type(4)));

#define T_LEN 1024
#define B_SZ  256
#define H_DIM 256
#define M_ROWS (T_LEN * B_SZ)   // 262144
#define MT     (M_ROWS / 32)    // 8192 tiles
#define NRB    16               // rnn blocks
#define NGB    240              // gemm blocks

// device-global weight/bias copies and sync flags
__device__ _Float16 gWx0[256 * 64];
__device__ _Float16 gWx1[256 * 256];
__device__ _Float16 gWih[256 * 256];
__device__ _Float16 gWh0[256 * 256];
__device__ _Float16 gWh1[256 * 256];
__device__ _Float16 gWg[64 * 256];
__device__ float gBx0[256], gBx1[256], gBih[256], gBh0[256], gBh1[256], gBg[64];
__device__ unsigned gZxFlag[MT];   // tile bm of zx ready
__device__ unsigned gProg[NRB];    // rnn block b: h_all[0..prog) complete

__device__ __forceinline__ float fast_tanh(float x) {
  float e = __expf(2.0f * x);
  return 1.0f - 2.0f / (e + 1.0f);
}

// sorted alpha assignment over 256 units: 86 x 0.001, 85 x 0.01, 85 x 0.1
__device__ __forceinline__ float alpha_of(int j) {
  return (j < 86) ? 0.001f : ((j < 171) ? 0.01f : 0.1f);
}

// barrier with LDS-only drain: global loads/stores stay in flight across it
__device__ __forceinline__ void lds_barrier() {
  asm volatile("s_waitcnt lgkmcnt(0)\n\ts_barrier" ::: "memory");
}

// ---------------------------------------------------------------------------
// prep: zero flags, copy weights (fp32 -> fp16 device globals) and biases.
// ---------------------------------------------------------------------------
__global__ void prep(const float* __restrict__ Wx0, const float* __restrict__ Wx1,
                     const float* __restrict__ Wih, const float* __restrict__ Wh0,
                     const float* __restrict__ Wh1, const float* __restrict__ Wg,
                     const float* __restrict__ bx0, const float* __restrict__ bx1,
                     const float* __restrict__ bih, const float* __restrict__ bh0,
                     const float* __restrict__ bh1, const float* __restrict__ bg) {
  const int i = blockIdx.x * blockDim.x + threadIdx.x;  // 65536 threads
  if (i < MT) gZxFlag[i] = 0u;
  if (i < NRB) gProg[i] = 0u;
  if (i < 16384) { gWx0[i] = (_Float16)Wx0[i]; gWg[i] = (_Float16)Wg[i]; }
  if (i < 65536) {
    gWx1[i] = (_Float16)Wx1[i];
    gWih[i] = (_Float16)Wih[i];
    gWh0[i] = (_Float16)Wh0[i];
    gWh1[i] = (_Float16)Wh1[i];
  }
  if (i < 256) {
    gBx0[i] = bx0[i]; gBx1[i] = bx1[i]; gBih[i] = bih[i];
    gBh0[i] = bh0[i]; gBh1[i] = bh1[i];
  }
  if (i < 64) gBg[i] = bg[i];
}

// ---------------------------------------------------------------------------
// Fused GEMM stage: Ch[32][264] = act(Ah @ W^T + b). 8 waves, 32 cols/wave.
// W fp16 [256][K] from device globals (L2-hot). MFMA 16x16x32 layouts as
// verified: A[m=l15][k=8*quad+i], B[k=8*quad+i][n=l15], D row=quad*4+rg.
// ---------------------------------------------------------------------------
template <int KCH, bool TANH>
__device__ __forceinline__ void stage_tile(const _Float16 (*__restrict__ Ah)[264],
                                           _Float16 (*__restrict__ Ch)[264],
                                           const _Float16* __restrict__ W,
                                           const float* __restrict__ bias,
                                           const int tid) {
  constexpr int K = KCH * 32;
  const int lane = tid & 63, wave = tid >> 6, l15 = lane & 15, quad = lane >> 4;
  const int jw = wave * 32;

  halfx8 Bf[2][KCH];
  float bcol[2];
  int jj[2];
#pragma unroll
  for (int nt = 0; nt < 2; nt++) {
    jj[nt] = jw + nt * 16 + l15;
    bcol[nt] = bias[jj[nt]];
#pragma unroll
    for (int ks = 0; ks < KCH; ks++)
      Bf[nt][ks] = *(const halfx8*)(W + (size_t)jj[nt] * K + ks * 32 + quad * 8);
  }

  f32x4 acc[2][2];
#pragma unroll
  for (int mi = 0; mi < 2; mi++)
#pragma unroll
    for (int nt = 0; nt < 2; nt++) acc[mi][nt] = (f32x4){0.f, 0.f, 0.f, 0.f};

#pragma unroll
  for (int ks = 0; ks < KCH; ks++)
#pragma unroll
    for (int mi = 0; mi < 2; mi++) {
      halfx8 a = *(const halfx8*)&Ah[mi * 16 + l15][ks * 32 + quad * 8];
#pragma unroll
      for (int nt = 0; nt < 2; nt++)
        acc[mi][nt] = __builtin_amdgcn_mfma_f32_16x16x32_f16(a, Bf[nt][ks], acc[mi][nt], 0, 0, 0);
    }

#pragma unroll
  for (int mi = 0; mi < 2; mi++)
#pragma unroll
    for (int nt = 0; nt < 2; nt++)
#pragma unroll
      for (int rg = 0; rg < 4; rg++) {
        float v = acc[mi][nt][rg] + bcol[nt];
        if (TANH) v = fast_tanh(v);
        Ch[mi * 16 + quad * 4 + rg][jj[nt]] = (_Float16)v;
      }
}

// Same, but epilogue to global fp16 [*,256] rows (zx output; no tanh).
__device__ __forceinline__ void stage_zx(const _Float16 (*__restrict__ Ah)[264],
                                         _Float16* __restrict__ C,
                                         const _Float16* __restrict__ W,
                                         const float* __restrict__ bias,
                                         const int tid) {
  constexpr int KCH = 8, K = 256;
  const int lane = tid & 63, wave = tid >> 6, l15 = lane & 15, quad = lane >> 4;
  const int jw = wave * 32;

  halfx8 Bf[2][KCH];
  float bcol[2];
  int jj[2];
#pragma unroll
  for (int nt = 0; nt < 2; nt++) {
    jj[nt] = jw + nt * 16 + l15;
    bcol[nt] = bias[jj[nt]];
#pragma unroll
    for (int ks = 0; ks < KCH; ks++)
      Bf[nt][ks] = *(const halfx8*)(W + (size_t)jj[nt] * K + ks * 32 + quad * 8);
  }

  f32x4 acc[2][2];
#pragma unroll
  for (int mi = 0; mi < 2; mi++)
#pragma unroll
    for (int nt = 0; nt < 2; nt++) acc[mi][nt] = (f32x4){0.f, 0.f, 0.f, 0.f};

#pragma unroll
  for (int ks = 0; ks < KCH; ks++)
#pragma unroll
    for (int mi = 0; mi < 2; mi++) {
      halfx8 a = *(const halfx8*)&Ah[mi * 16 + l15][ks * 32 + quad * 8];
#pragma unroll
      for (int nt = 0; nt < 2; nt++)
        acc[mi][nt] = __builtin_amdgcn_mfma_f32_16x16x32_f16(a, Bf[nt][ks], acc[mi][nt], 0, 0, 0);
    }

#pragma unroll
  for (int mi = 0; mi < 2; mi++)
#pragma unroll
    for (int nt = 0; nt < 2; nt++)
#pragma unroll
      for (int rg = 0; rg < 4; rg++) {
        const int row = mi * 16 + quad * 4 + rg;
        C[(size_t)row * 256 + jj[nt]] = (_Float16)(acc[mi][nt][rg] + bcol[nt]);
      }
}

// Final projection tile: out[32,64] fp32 = Ah @ Wg^T + bg. Waves 0-3 only.
__device__ __forceinline__ void stage_out(const _Float16 (*__restrict__ Ah)[264],
                                          float* __restrict__ C,
                                          const _Float16* __restrict__ W,
                                          const float* __restrict__ bias,
                                          const int tid) {
  const int lane = tid & 63, wave = tid >> 6, l15 = lane & 15, quad = lane >> 4;
  if (wave < 4) {
    const int jcol = wave * 16 + l15;
    halfx8 Bf[8];
#pragma unroll
    for (int ks = 0; ks < 8; ks++)
      Bf[ks] = *(const halfx8*)(W + (size_t)jcol * 256 + ks * 32 + quad * 8);
    const float bc = bias[jcol];
    f32x4 acc[2];
#pragma unroll
    for (int mi = 0; mi < 2; mi++) acc[mi] = (f32x4){0.f, 0.f, 0.f, 0.f};
#pragma unroll
    for (int ks = 0; ks < 8; ks++)
#pragma unroll
      for (int mi = 0; mi < 2; mi++) {
        halfx8 a = *(const halfx8*)&Ah[mi * 16 + l15][ks * 32 + quad * 8];
        acc[mi] = __builtin_amdgcn_mfma_f32_16x16x32_f16(a, Bf[ks], acc[mi], 0, 0, 0);
      }
#pragma unroll
    for (int mi = 0; mi < 2; mi++)
#pragma unroll
      for (int rg = 0; rg < 4; rg++)
        C[(size_t)(mi * 16 + quad * 4 + rg) * 64 + jcol] = acc[mi][rg] + bc;
  }
}

// ---------------------------------------------------------------------------
// rnn block body: round-7 loop (8 waves, 2/SIMD, swapped operands) plus
// zx-flag polling (every 8 steps, batched relaxed loads + one acquire) and
// h-progress publish (every 8 steps, vmcnt-drain barrier + release store).
// ---------------------------------------------------------------------------
__device__ void rnn_block(const _Float16* __restrict__ zx,
                          _Float16* __restrict__ h_all,
                          const float* __restrict__ Whh,
                          const float* __restrict__ bhh_p,
                          _Float16 (*__restrict__ lds)[264],  // >= 32 rows of 264
                          const int bid) {
  _Float16(*hB)[16][264] = reinterpret_cast<_Float16(*)[16][264]>(&lds[0][0]);

  const int tid  = threadIdx.x;
  const int lane = tid & 63;
  const int wave = tid >> 6;   // 0..7, owns 32 h-columns
  const int l15  = lane & 15;
  const int quad = lane >> 4;
  const int r0   = bid * 16;
  const int b2   = bid >> 1;   // zx tile row-group
  const int jb   = wave * 32;

  // A-fragments: Whh rows j = jb + mt*16 + l15
  halfx8 Af[2][8];
#pragma unroll
  for (int mt = 0; mt < 2; mt++) {
    const int j = jb + mt * 16 + l15;
#pragma unroll
    for (int ks = 0; ks < 8; ks++) {
      const float* wp = Whh + (size_t)j * H_DIM + ks * 32 + quad * 8;
      float4 w0 = *(const float4*)wp;
      float4 w1 = *(const float4*)(wp + 4);
      halfx8 f;
      f[0] = (_Float16)w0.x; f[1] = (_Float16)w0.y;
      f[2] = (_Float16)w0.z; f[3] = (_Float16)w0.w;
      f[4] = (_Float16)w1.x; f[5] = (_Float16)w1.y;
      f[6] = (_Float16)w1.z; f[7] = (_Float16)w1.w;
      Af[mt][ks] = f;
    }
  }

  float bj[2][4], aj[2][4], oma[2][4];
#pragma unroll
  for (int mt = 0; mt < 2; mt++)
#pragma unroll
    for (int rg = 0; rg < 4; rg++) {
      const int j = jb + mt * 16 + quad * 4 + rg;
      bj[mt][rg]  = bhh_p[j];
      aj[mt][rg]  = alpha_of(j);
      oma[mt][rg] = 1.0f - aj[mt][rg];
    }

  for (int i = tid; i < 16 * 264; i += 512) (&hB[0][0][0])[i] = (_Float16)0.0f;
  __syncthreads();

  const _Float16* rdp[2] = {&hB[0][l15][quad * 8], &hB[1][l15][quad * 8]};
  _Float16*       wrp[2] = {&hB[1][l15][jb + quad * 4], &hB[0][l15][jb + quad * 4]};

  constexpr int STRIDE = B_SZ * H_DIM;
  const _Float16* zp = zx    + (size_t)(r0 + l15) * H_DIM + jb + quad * 4;
  _Float16*       hp = h_all + (size_t)(r0 + l15) * H_DIM + jb + quad * 4;

  // poll: ensure zx[tbase .. tbase+7] tiles for this row-group are published
  auto poll8 = [&](int tbase) {
    bool ok = false;
    while (!ok) {
      ok = true;
#pragma unroll
      for (int i = 0; i < 8; i++) {
        const int tt = tbase + i;
        if (tt < T_LEN)
          ok &= (__hip_atomic_load(&gZxFlag[tt * 8 + b2], __ATOMIC_RELAXED,
                                   __HIP_MEMORY_SCOPE_AGENT) != 0u);
      }
      if (!ok) __builtin_amdgcn_s_sleep(2);
    }
    // one acquire to order subsequent zx loads (invalidates stale cache)
    unsigned v = __hip_atomic_load(&gZxFlag[(tbase < T_LEN ? tbase : 0) * 8 + b2],
                                   __ATOMIC_ACQUIRE, __HIP_MEMORY_SCOPE_AGENT);
    asm volatile("" ::"v"(v));
  };

  poll8(0);  // zx[0..7] ready before prologue loads

  float  zc[2][4];
  halfx4 zA[2];
  {
#pragma unroll
    for (int mt = 0; mt < 2; mt++) {
      halfx4 z0 = *(const halfx4*)(zp + mt * 16);
      zA[mt]    = *(const halfx4*)(zp + mt * 16 + STRIDE);
#pragma unroll
      for (int rg = 0; rg < 4; rg++) zc[mt][rg] = (float)z0[rg];
    }
    zp += 2 * (size_t)STRIDE;
  }

  float  hreg[2][4];
  halfx4 hh4[2];
#pragma unroll
  for (int mt = 0; mt < 2; mt++)
#pragma unroll
    for (int rg = 0; rg < 4; rg++) { hreg[mt][rg] = 0.0f; hh4[mt][rg] = (_Float16)0.0f; }

  auto step = [&](int p, bool pub, unsigned pval) {
    halfx4 znew[2];
#pragma unroll
    for (int mt = 0; mt < 2; mt++) znew[mt] = *(const halfx4*)(zp + mt * 16);
    zp += STRIDE;

    const _Float16* rd = rdp[p];
    halfx8 hb[8];
#pragma unroll
    for (int ks = 0; ks < 8; ks++) hb[ks] = *(const halfx8*)(rd + ks * 32);

    f32x4 acc[2];
#pragma unroll
    for (int mt = 0; mt < 2; mt++) acc[mt] = (f32x4){0.f, 0.f, 0.f, 0.f};
#pragma unroll
    for (int ks = 0; ks < 8; ks++)
#pragma unroll
      for (int mt = 0; mt < 2; mt++)
        acc[mt] = __builtin_amdgcn_mfma_f32_16x16x32_f16(Af[mt][ks], hb[ks], acc[mt], 0, 0, 0);

    _Float16* wr = wrp[p];
#pragma unroll
    for (int mt = 0; mt < 2; mt++) {
      halfx4 hnew;
#pragma unroll
      for (int rg = 0; rg < 4; rg++) {
        float hr = fast_tanh(zc[mt][rg] + acc[mt][rg] + bj[mt][rg]);
        float hn = oma[mt][rg] * hreg[mt][rg] + aj[mt][rg] * hr;
        hreg[mt][rg] = hn;
        hnew[rg] = (_Float16)hn;
      }
      *(halfx4*)(hp + mt * 16) = hh4[mt];   // h_all[t] = pre-update h_t
      hh4[mt] = hnew;
      *(halfx4*)(wr + mt * 16) = hnew;      // next step's B operand
    }
    hp += STRIDE;

    if (pub) {
      // full drain so all waves' h_all stores are complete, then release
      asm volatile("s_waitcnt vmcnt(0) lgkmcnt(0)\n\ts_barrier" ::: "memory");
      if (tid == 0) {
        __threadfence();
        __hip_atomic_store(&gProg[bid], pval, __ATOMIC_RELEASE, __HIP_MEMORY_SCOPE_AGENT);
      }
    } else {
      lds_barrier();
    }

#pragma unroll
    for (int mt = 0; mt < 2; mt++) {
#pragma unroll
      for (int rg = 0; rg < 4; rg++) zc[mt][rg] = (float)zA[mt][rg];
      zA[mt] = znew[mt];
    }
  };

  for (int it = 0; it < T_LEN / 2; ++it) {
    const int t0 = 2 * it;
    if ((it & 3) == 0) poll8(t0 + 2);        // covers loads of steps t0..t0+7
    step(0, false, 0u);
    step(1, (it & 3) == 3, (unsigned)(t0 + 2));  // prog = t0+2 = (t0+1)+1
  }
}

// ---------------------------------------------------------------------------
// mega kernel
// ---------------------------------------------------------------------------
__global__ __launch_bounds__(512, 1)
void mega(const float* __restrict__ x, _Float16* __restrict__ bufA,
          _Float16* __restrict__ bufB, float* __restrict__ out,
          const float* __restrict__ Whh, const float* __restrict__ bhh_p) {
  __shared__ __attribute__((aligned(16))) _Float16 lds[2][32][264];
  const int tid = threadIdx.x;

  if (blockIdx.x < NRB) {
    rnn_block(bufA, bufB, Whh, bhh_p, lds[0], blockIdx.x);
    return;
  }

  const int g = blockIdx.x - NRB;  // 0..NGB-1
  _Float16(*Ah)[264] = lds[0];
  _Float16(*Bh)[264] = lds[1];

  // ---- phase A: x -> feat1 -> feat2 -> zx (+flag), per tile ----
  for (int bm = g; bm < MT; bm += NGB) {
    {  // stage x tile (32 x 64 fp32 -> fp16 LDS)
      const int srow = tid >> 4, sk4 = tid & 15;
      float4 tv = *(const float4*)(x + (size_t)(bm * 32 + srow) * 64 + sk4 * 4);
      halfx4 h;
      h[0] = (_Float16)tv.x; h[1] = (_Float16)tv.y;
      h[2] = (_Float16)tv.z; h[3] = (_Float16)tv.w;
      *(halfx4*)&Ah[srow][sk4 * 4] = h;
    }
    lds_barrier();
    stage_tile<2, true>(Ah, Bh, gWx0, gBx0, tid);
    lds_barrier();
    stage_tile<8, true>(Bh, Ah, gWx1, gBx1, tid);
    lds_barrier();
    stage_zx(Ah, bufA + (size_t)bm * 32 * 256, gWih, gBih, tid);
    __syncthreads();  // drains vmcnt: all zx stores of this tile complete
    if (tid == 0) {
      __threadfence();
      __hip_atomic_store(&gZxFlag[bm], 1u, __ATOMIC_RELEASE, __HIP_MEMORY_SCOPE_AGENT);
    }
    __syncthreads();
  }

  // ---- phase B: h_all -> d1 -> d2 -> out, gated on rnn progress ----
  for (int bm = g; bm < MT; bm += NGB) {
    const int t = bm >> 3, b2 = bm & 7;
    const unsigned need = (unsigned)(t + 1);
    if (tid == 0) {
      while (__hip_atomic_load(&gProg[2 * b2], __ATOMIC_ACQUIRE,
                               __HIP_MEMORY_SCOPE_AGENT) < need)
        __builtin_amdgcn_s_sleep(8);
      while (__hip_atomic_load(&gProg[2 * b2 + 1], __ATOMIC_ACQUIRE,
                               __HIP_MEMORY_SCOPE_AGENT) < need)
        __builtin_amdgcn_s_sleep(8);
    }
    __syncthreads();
    {  // stage h tile (32 x 256 fp16)
      const int srow = tid >> 4, sk4 = tid & 15;
      const _Float16* hsrc = bufB + (size_t)bm * 32 * 256 + (size_t)srow * 256 + sk4 * 16;
      halfx8 t0 = *(const halfx8*)hsrc;
      halfx8 t1 = *(const halfx8*)(hsrc + 8);
      *(halfx8*)&Ah[srow][sk4 * 16] = t0;
      *(halfx8*)&Ah[srow][sk4 * 16 + 8] = t1;
    }
    lds_barrier();
    stage_tile<8, true>(Ah, Bh, gWh0, gBh0, tid);
    lds_barrier();
    stage_tile<8, true>(Bh, Ah, gWh1, gBh1, tid);
    lds_barrier();
    stage_out(Ah, out + (size_t)bm * 32 * 64, gWg, gBg, tid);
    lds_barrier();  // stage_out's Ah reads done before next tile's staging
  }
}

// ---------------------------------------------------------------------------
extern "C" void kernel_launch(void* const* d_in, const int* in_sizes, int n_in,
                              void* d_out, int out_size, void* d_ws, size_t ws_size,
                              hipStream_t stream) {
  const float* x   = (const float*)d_in[0];
  const float* Wx0 = (const float*)d_in[1];
  const float* bx0 = (const float*)d_in[2];
  const float* Wx1 = (const float*)d_in[3];
  const float* bx1 = (const float*)d_in[4];
  const float* Wih = (const float*)d_in[5];
  const float* Whh = (const float*)d_in[6];
  const float* bih = (const float*)d_in[7];
  const float* bhh = (const float*)d_in[8];
  const float* Wh0 = (const float*)d_in[9];
  const float* bh0 = (const float*)d_in[10];
  const float* Wh1 = (const float*)d_in[11];
  const float* bh1 = (const float*)d_in[12];
  const float* Wg  = (const float*)d_in[13];
  const float* bg  = (const float*)d_in[14];
  float* out = (float*)d_out;

  // two fp16 ping-pong halves, 128 MiB each (ws >= 256 MiB)
  _Float16* bufA = (_Float16*)d_ws;                    // zx [T,B,H]
  _Float16* bufB = bufA + (size_t)M_ROWS * 256;        // h_all [T,B,H]

  prep<<<256, 256, 0, stream>>>(Wx0, Wx1, Wih, Wh0, Wh1, Wg,
                                bx0, bx1, bih, bh0, bh1, bg);
  mega<<<NRB + NGB, 512, 0, stream>>>(x, bufA, bufB, out, Whh, bhh);
}

// Round 4
// 1548.116 us; speedup vs baseline: 2.3704x; 2.3704x over previous
//
#include <hip/hip_runtime.h>
#include <cstddef>

// ---------------------------------------------------------------------------
// MT_RNN round 9: de-risked overlap.
//   prep : weights -> fp16 device globals, zero progress flags
//   pre  : fused (1)+(2)+(3)  x -> feat1 -> feat2 -> zx [T,B,H], all 256 CUs
//   mega2: blocks 0-15  = rnn recurrence (zx ready; NO polling),
//          blocks 16-255 = fused (5)+(6)+(7) per tile, gated on rnn progress.
//
// Round-8 post-mortem: phase B spun with ACQUIRE loads -> buffer_inv storm
// (240 blocks x ~1ms continuous L1/L2 invalidation across all XCDs) ->
// everything latency-bound, 3.7x regression. Fixes here:
//   - phase B: RELAXED spin + s_sleep, ONE acquire after success
//   - rnn h_all stores are NON-TEMPORAL (write to coherence point, no dirty
//     L2) so the RELEASE publish's implicit wbl2 is near-free
//   - publish every 16 steps; no __threadfence; no zx polling (pre runs first)
// Buffers: bufA = zx [T,B,H] fp16; bufB = h_all [T,B,H] fp16 (ws >= 256MB).
// Deadlock-free: 256 blocks all co-resident; wait graph acyclic (B <- rnn).
// ---------------------------------------------------------------------------

typedef _Float16 halfx8 __attribute__((ext_vector_type(8)));
typedef _Float16 halfx4 __attribute__((ext_vector_type(4)));
typedef float    f32x4  __attribute__((ext_vector_type(4)));

#define T_LEN 1024
#define B_SZ  256
#define H_DIM 256
#define M_ROWS (T_LEN * B_SZ)   // 262144
#define MT     (M_ROWS / 32)    // 8192 tiles
#define NRB    16               // rnn blocks
#define NGB    240              // gemm blocks

__device__ _Float16 gWx0[256 * 64];
__device__ _Float16 gWx1[256 * 256];
__device__ _Float16 gWih[256 * 256];
__device__ _Float16 gWh0[256 * 256];
__device__ _Float16 gWh1[256 * 256];
__device__ _Float16 gWg[64 * 256];
__device__ float gBx0[256], gBx1[256], gBih[256], gBh0[256], gBh1[256], gBg[64];
__device__ unsigned gProg[NRB];   // rnn block b: h_all[0..prog) complete

__device__ __forceinline__ float fast_tanh(float x) {
  float e = __expf(2.0f * x);
  return 1.0f - 2.0f / (e + 1.0f);
}

// sorted alpha assignment over 256 units: 86 x 0.001, 85 x 0.01, 85 x 0.1
__device__ __forceinline__ float alpha_of(int j) {
  return (j < 86) ? 0.001f : ((j < 171) ? 0.01f : 0.1f);
}

// barrier with LDS-only drain: global loads/stores stay in flight across it
__device__ __forceinline__ void lds_barrier() {
  asm volatile("s_waitcnt lgkmcnt(0)\n\ts_barrier" ::: "memory");
}

// ---------------------------------------------------------------------------
// prep: zero flags, copy weights (fp32 -> fp16 device globals) and biases.
// ---------------------------------------------------------------------------
__global__ void prep(const float* __restrict__ Wx0, const float* __restrict__ Wx1,
                     const float* __restrict__ Wih, const float* __restrict__ Wh0,
                     const float* __restrict__ Wh1, const float* __restrict__ Wg,
                     const float* __restrict__ bx0, const float* __restrict__ bx1,
                     const float* __restrict__ bih, const float* __restrict__ bh0,
                     const float* __restrict__ bh1, const float* __restrict__ bg) {
  const int i = blockIdx.x * blockDim.x + threadIdx.x;  // 65536 threads
  if (i < NRB) gProg[i] = 0u;
  if (i < 16384) { gWx0[i] = (_Float16)Wx0[i]; gWg[i] = (_Float16)Wg[i]; }
  if (i < 65536) {
    gWx1[i] = (_Float16)Wx1[i];
    gWih[i] = (_Float16)Wih[i];
    gWh0[i] = (_Float16)Wh0[i];
    gWh1[i] = (_Float16)Wh1[i];
  }
  if (i < 256) {
    gBx0[i] = bx0[i]; gBx1[i] = bx1[i]; gBih[i] = bih[i];
    gBh0[i] = bh0[i]; gBh1[i] = bh1[i];
  }
  if (i < 64) gBg[i] = bg[i];
}

// ---------------------------------------------------------------------------
// Fused GEMM stage: Ch[32][264] = act(Ah @ W^T + b). 8 waves, 32 cols/wave.
// W fp16 [256][K] device globals (L2-hot). MFMA 16x16x32 layouts (verified):
//   A[m=l15][k=8*quad+i], B[k=8*quad+i][n=l15], D row=quad*4+rg.
// ---------------------------------------------------------------------------
template <int KCH, bool TANH>
__device__ __forceinline__ void stage_tile(const _Float16 (*__restrict__ Ah)[264],
                                           _Float16 (*__restrict__ Ch)[264],
                                           const _Float16* __restrict__ W,
                                           const float* __restrict__ bias,
                                           const int tid) {
  constexpr int K = KCH * 32;
  const int lane = tid & 63, wave = tid >> 6, l15 = lane & 15, quad = lane >> 4;
  const int jw = wave * 32;

  halfx8 Bf[2][KCH];
  float bcol[2];
  int jj[2];
#pragma unroll
  for (int nt = 0; nt < 2; nt++) {
    jj[nt] = jw + nt * 16 + l15;
    bcol[nt] = bias[jj[nt]];
#pragma unroll
    for (int ks = 0; ks < KCH; ks++)
      Bf[nt][ks] = *(const halfx8*)(W + (size_t)jj[nt] * K + ks * 32 + quad * 8);
  }

  f32x4 acc[2][2];
#pragma unroll
  for (int mi = 0; mi < 2; mi++)
#pragma unroll
    for (int nt = 0; nt < 2; nt++) acc[mi][nt] = (f32x4){0.f, 0.f, 0.f, 0.f};

#pragma unroll
  for (int ks = 0; ks < KCH; ks++)
#pragma unroll
    for (int mi = 0; mi < 2; mi++) {
      halfx8 a = *(const halfx8*)&Ah[mi * 16 + l15][ks * 32 + quad * 8];
#pragma unroll
      for (int nt = 0; nt < 2; nt++)
        acc[mi][nt] = __builtin_amdgcn_mfma_f32_16x16x32_f16(a, Bf[nt][ks], acc[mi][nt], 0, 0, 0);
    }

#pragma unroll
  for (int mi = 0; mi < 2; mi++)
#pragma unroll
    for (int nt = 0; nt < 2; nt++)
#pragma unroll
      for (int rg = 0; rg < 4; rg++) {
        float v = acc[mi][nt][rg] + bcol[nt];
        if (TANH) v = fast_tanh(v);
        Ch[mi * 16 + quad * 4 + rg][jj[nt]] = (_Float16)v;
      }
}

// Same, but epilogue to global fp16 [*,256] rows (zx output; no tanh).
__device__ __forceinline__ void stage_zx(const _Float16 (*__restrict__ Ah)[264],
                                         _Float16* __restrict__ C,
                                         const _Float16* __restrict__ W,
                                         const float* __restrict__ bias,
                                         const int tid) {
  constexpr int KCH = 8, K = 256;
  const int lane = tid & 63, wave = tid >> 6, l15 = lane & 15, quad = lane >> 4;
  const int jw = wave * 32;

  halfx8 Bf[2][KCH];
  float bcol[2];
  int jj[2];
#pragma unroll
  for (int nt = 0; nt < 2; nt++) {
    jj[nt] = jw + nt * 16 + l15;
    bcol[nt] = bias[jj[nt]];
#pragma unroll
    for (int ks = 0; ks < KCH; ks++)
      Bf[nt][ks] = *(const halfx8*)(W + (size_t)jj[nt] * K + ks * 32 + quad * 8);
  }

  f32x4 acc[2][2];
#pragma unroll
  for (int mi = 0; mi < 2; mi++)
#pragma unroll
    for (int nt = 0; nt < 2; nt++) acc[mi][nt] = (f32x4){0.f, 0.f, 0.f, 0.f};

#pragma unroll
  for (int ks = 0; ks < KCH; ks++)
#pragma unroll
    for (int mi = 0; mi < 2; mi++) {
      halfx8 a = *(const halfx8*)&Ah[mi * 16 + l15][ks * 32 + quad * 8];
#pragma unroll
      for (int nt = 0; nt < 2; nt++)
        acc[mi][nt] = __builtin_amdgcn_mfma_f32_16x16x32_f16(a, Bf[nt][ks], acc[mi][nt], 0, 0, 0);
    }

#pragma unroll
  for (int mi = 0; mi < 2; mi++)
#pragma unroll
    for (int nt = 0; nt < 2; nt++)
#pragma unroll
      for (int rg = 0; rg < 4; rg++) {
        const int row = mi * 16 + quad * 4 + rg;
        C[(size_t)row * 256 + jj[nt]] = (_Float16)(acc[mi][nt][rg] + bcol[nt]);
      }
}

// Final projection tile: out[32,64] fp32 = Ah @ Wg^T + bg. Waves 0-3 only.
__device__ __forceinline__ void stage_out(const _Float16 (*__restrict__ Ah)[264],
                                          float* __restrict__ C,
                                          const _Float16* __restrict__ W,
                                          const float* __restrict__ bias,
                                          const int tid) {
  const int lane = tid & 63, wave = tid >> 6, l15 = lane & 15, quad = lane >> 4;
  if (wave < 4) {
    const int jcol = wave * 16 + l15;
    halfx8 Bf[8];
#pragma unroll
    for (int ks = 0; ks < 8; ks++)
      Bf[ks] = *(const halfx8*)(W + (size_t)jcol * 256 + ks * 32 + quad * 8);
    const float bc = bias[jcol];
    f32x4 acc[2];
#pragma unroll
    for (int mi = 0; mi < 2; mi++) acc[mi] = (f32x4){0.f, 0.f, 0.f, 0.f};
#pragma unroll
    for (int ks = 0; ks < 8; ks++)
#pragma unroll
      for (int mi = 0; mi < 2; mi++) {
        halfx8 a = *(const halfx8*)&Ah[mi * 16 + l15][ks * 32 + quad * 8];
        acc[mi] = __builtin_amdgcn_mfma_f32_16x16x32_f16(a, Bf[ks], acc[mi], 0, 0, 0);
      }
#pragma unroll
    for (int mi = 0; mi < 2; mi++)
#pragma unroll
      for (int rg = 0; rg < 4; rg++)
        C[(size_t)(mi * 16 + quad * 4 + rg) * 64 + jcol] = acc[mi][rg] + bc;
  }
}

// ---------------------------------------------------------------------------
// pre: fused (1)+(2)+(3), per 32-row tile, intermediates in LDS.
// ---------------------------------------------------------------------------
__global__ __launch_bounds__(512, 2)
void pre(const float* __restrict__ x, _Float16* __restrict__ zx) {
  __shared__ __attribute__((aligned(16))) _Float16 lds[2][32][264];
  const int tid = threadIdx.x;
  _Float16(*Ah)[264] = lds[0];
  _Float16(*Bh)[264] = lds[1];

  for (int bm = blockIdx.x; bm < MT; bm += gridDim.x) {
    {  // stage x tile (32 x 64 fp32 -> fp16 LDS)
      const int srow = tid >> 4, sk4 = tid & 15;
      float4 tv = *(const float4*)(x + (size_t)(bm * 32 + srow) * 64 + sk4 * 4);
      halfx4 h;
      h[0] = (_Float16)tv.x; h[1] = (_Float16)tv.y;
      h[2] = (_Float16)tv.z; h[3] = (_Float16)tv.w;
      *(halfx4*)&Ah[srow][sk4 * 4] = h;
    }
    lds_barrier();
    stage_tile<2, true>(Ah, Bh, gWx0, gBx0, tid);
    lds_barrier();
    stage_tile<8, true>(Bh, Ah, gWx1, gBx1, tid);
    lds_barrier();
    stage_zx(Ah, zx + (size_t)bm * 32 * 256, gWih, gBih, tid);
    lds_barrier();  // Ah reads done before next tile's x staging
  }
}

// ---------------------------------------------------------------------------
// rnn block body: round-7 loop (8 waves, 2/SIMD, swapped operands).
// h_all stores are NON-TEMPORAL (straight to coherence point -> no dirty L2,
// publish wbl2 near-free). Progress published every 16 steps: full-drain
// barrier + agent-scope RELEASE store by tid 0.
// ---------------------------------------------------------------------------
__device__ void rnn_block(const _Float16* __restrict__ zx,
                          _Float16* __restrict__ h_all,
                          const float* __restrict__ Whh,
                          const float* __restrict__ bhh_p,
                          _Float16 (*__restrict__ lds)[264],
                          const int bid) {
  _Float16(*hB)[16][264] = reinterpret_cast<_Float16(*)[16][264]>(&lds[0][0]);

  const int tid  = threadIdx.x;
  const int lane = tid & 63;
  const int wave = tid >> 6;   // 0..7, owns 32 h-columns
  const int l15  = lane & 15;
  const int quad = lane >> 4;
  const int r0   = bid * 16;
  const int jb   = wave * 32;

  // A-fragments: Whh rows j = jb + mt*16 + l15
  halfx8 Af[2][8];
#pragma unroll
  for (int mt = 0; mt < 2; mt++) {
    const int j = jb + mt * 16 + l15;
#pragma unroll
    for (int ks = 0; ks < 8; ks++) {
      const float* wp = Whh + (size_t)j * H_DIM + ks * 32 + quad * 8;
      float4 w0 = *(const float4*)wp;
      float4 w1 = *(const float4*)(wp + 4);
      halfx8 f;
      f[0] = (_Float16)w0.x; f[1] = (_Float16)w0.y;
      f[2] = (_Float16)w0.z; f[3] = (_Float16)w0.w;
      f[4] = (_Float16)w1.x; f[5] = (_Float16)w1.y;
      f[6] = (_Float16)w1.z; f[7] = (_Float16)w1.w;
      Af[mt][ks] = f;
    }
  }

  float bj[2][4], aj[2][4], oma[2][4];
#pragma unroll
  for (int mt = 0; mt < 2; mt++)
#pragma unroll
    for (int rg = 0; rg < 4; rg++) {
      const int j = jb + mt * 16 + quad * 4 + rg;
      bj[mt][rg]  = bhh_p[j];
      aj[mt][rg]  = alpha_of(j);
      oma[mt][rg] = 1.0f - aj[mt][rg];
    }

  for (int i = tid; i < 16 * 264; i += 512) (&hB[0][0][0])[i] = (_Float16)0.0f;
  __syncthreads();

  const _Float16* rdp[2] = {&hB[0][l15][quad * 8], &hB[1][l15][quad * 8]};
  _Float16*       wrp[2] = {&hB[1][l15][jb + quad * 4], &hB[0][l15][jb + quad * 4]};

  constexpr int STRIDE = B_SZ * H_DIM;
  const _Float16* zp = zx    + (size_t)(r0 + l15) * H_DIM + jb + quad * 4;
  _Float16*       hp = h_all + (size_t)(r0 + l15) * H_DIM + jb + quad * 4;

  float  zc[2][4];
  halfx4 zA[2];
  {
#pragma unroll
    for (int mt = 0; mt < 2; mt++) {
      halfx4 z0 = *(const halfx4*)(zp + mt * 16);
      zA[mt]    = *(const halfx4*)(zp + mt * 16 + STRIDE);
#pragma unroll
      for (int rg = 0; rg < 4; rg++) zc[mt][rg] = (float)z0[rg];
    }
    zp += 2 * (size_t)STRIDE;
  }

  float  hreg[2][4];
  halfx4 hh4[2];
#pragma unroll
  for (int mt = 0; mt < 2; mt++)
#pragma unroll
    for (int rg = 0; rg < 4; rg++) { hreg[mt][rg] = 0.0f; hh4[mt][rg] = (_Float16)0.0f; }

  auto step = [&](int p, bool pub, unsigned pval) {
    halfx4 znew[2];
#pragma unroll
    for (int mt = 0; mt < 2; mt++) znew[mt] = *(const halfx4*)(zp + mt * 16);
    zp += STRIDE;

    const _Float16* rd = rdp[p];
    halfx8 hb[8];
#pragma unroll
    for (int ks = 0; ks < 8; ks++) hb[ks] = *(const halfx8*)(rd + ks * 32);

    f32x4 acc[2];
#pragma unroll
    for (int mt = 0; mt < 2; mt++) acc[mt] = (f32x4){0.f, 0.f, 0.f, 0.f};
#pragma unroll
    for (int ks = 0; ks < 8; ks++)
#pragma unroll
      for (int mt = 0; mt < 2; mt++)
        acc[mt] = __builtin_amdgcn_mfma_f32_16x16x32_f16(Af[mt][ks], hb[ks], acc[mt], 0, 0, 0);

    _Float16* wr = wrp[p];
#pragma unroll
    for (int mt = 0; mt < 2; mt++) {
      halfx4 hnew;
#pragma unroll
      for (int rg = 0; rg < 4; rg++) {
        float hr = fast_tanh(zc[mt][rg] + acc[mt][rg] + bj[mt][rg]);
        float hn = oma[mt][rg] * hreg[mt][rg] + aj[mt][rg] * hr;
        hreg[mt][rg] = hn;
        hnew[rg] = (_Float16)hn;
      }
      // h_all[t] = pre-update h_t, non-temporal (no dirty L2 line)
      __builtin_nontemporal_store(
          __builtin_bit_cast(unsigned long long, hh4[mt]),
          (unsigned long long*)(hp + mt * 16));
      hh4[mt] = hnew;
      *(halfx4*)(wr + mt * 16) = hnew;      // next step's B operand
    }
    hp += STRIDE;

    if (pub) {
      // all waves' h_all stores complete, then release progress
      asm volatile("s_waitcnt vmcnt(0) lgkmcnt(0)\n\ts_barrier" ::: "memory");
      if (tid == 0)
        __hip_atomic_store(&gProg[bid], pval, __ATOMIC_RELEASE,
                           __HIP_MEMORY_SCOPE_AGENT);
    } else {
      lds_barrier();
    }

#pragma unroll
    for (int mt = 0; mt < 2; mt++) {
#pragma unroll
      for (int rg = 0; rg < 4; rg++) zc[mt][rg] = (float)zA[mt][rg];
      zA[mt] = znew[mt];
    }
  };

  for (int it = 0; it < T_LEN / 2; ++it) {
    const int t0 = 2 * it;
    step(0, false, 0u);
    step(1, (it & 7) == 7, (unsigned)(t0 + 2));  // every 16 steps; final = 1024
  }
}

// ---------------------------------------------------------------------------
// mega2: rnn (blocks 0-15) + fused post-chain (blocks 16-255).
// ---------------------------------------------------------------------------
__global__ __launch_bounds__(512, 1)
void mega2(const _Float16* __restrict__ zx, _Float16* __restrict__ h_all,
           float* __restrict__ out, const float* __restrict__ Whh,
           const float* __restrict__ bhh_p) {
  __shared__ __attribute__((aligned(16))) _Float16 lds[2][32][264];
  const int tid = threadIdx.x;

  if (blockIdx.x < NRB) {
    rnn_block(zx, h_all, Whh, bhh_p, lds[0], blockIdx.x);
    return;
  }

  const int g = blockIdx.x - NRB;  // 0..NGB-1
  _Float16(*Ah)[264] = lds[0];
  _Float16(*Bh)[264] = lds[1];

  for (int bm = g; bm < MT; bm += NGB) {
    const int t = bm >> 3, b2 = bm & 7;
    const unsigned need = (unsigned)(t + 1);
    if (tid == 0) {
      // RELAXED spin (no cache invalidation), ONE acquire after success
      while (__hip_atomic_load(&gProg[2 * b2], __ATOMIC_RELAXED,
                               __HIP_MEMORY_SCOPE_AGENT) < need ||
             __hip_atomic_load(&gProg[2 * b2 + 1], __ATOMIC_RELAXED,
                               __HIP_MEMORY_SCOPE_AGENT) < need)
        __builtin_amdgcn_s_sleep(16);
      unsigned v = __hip_atomic_load(&gProg[2 * b2], __ATOMIC_ACQUIRE,
                                     __HIP_MEMORY_SCOPE_AGENT);
      asm volatile("" ::"v"(v));
    }
    __syncthreads();
    {  // stage h tile (32 x 256 fp16)
      const int srow = tid >> 4, sk4 = tid & 15;
      const _Float16* hsrc = h_all + (size_t)bm * 32 * 256 + (size_t)srow * 256 + sk4 * 16;
      halfx8 t0 = *(const halfx8*)hsrc;
      halfx8 t1 = *(const halfx8*)(hsrc + 8);
      *(halfx8*)&Ah[srow][sk4 * 16] = t0;
      *(halfx8*)&Ah[srow][sk4 * 16 + 8] = t1;
    }
    lds_barrier();
    stage_tile<8, true>(Ah, Bh, gWh0, gBh0, tid);
    lds_barrier();
    stage_tile<8, true>(Bh, Ah, gWh1, gBh1, tid);
    lds_barrier();
    stage_out(Ah, out + (size_t)bm * 32 * 64, gWg, gBg, tid);
    lds_barrier();  // stage_out's Ah reads done before next tile's staging
  }
}

// ---------------------------------------------------------------------------
extern "C" void kernel_launch(void* const* d_in, const int* in_sizes, int n_in,
                              void* d_out, int out_size, void* d_ws, size_t ws_size,
                              hipStream_t stream) {
  const float* x   = (const float*)d_in[0];
  const float* Wx0 = (const float*)d_in[1];
  const float* bx0 = (const float*)d_in[2];
  const float* Wx1 = (const float*)d_in[3];
  const float* bx1 = (const float*)d_in[4];
  const float* Wih = (const float*)d_in[5];
  const float* Whh = (const float*)d_in[6];
  const float* bih = (const float*)d_in[7];
  const float* bhh = (const float*)d_in[8];
  const float* Wh0 = (const float*)d_in[9];
  const float* bh0 = (const float*)d_in[10];
  const float* Wh1 = (const float*)d_in[11];
  const float* bh1 = (const float*)d_in[12];
  const float* Wg  = (const float*)d_in[13];
  const float* bg  = (const float*)d_in[14];
  float* out = (float*)d_out;

  // two fp16 ping-pong halves, 128 MiB each (ws >= 256 MiB)
  _Float16* bufA = (_Float16*)d_ws;                // zx    [T,B,H]
  _Float16* bufB = bufA + (size_t)M_ROWS * 256;    // h_all [T,B,H]

  prep<<<256, 256, 0, stream>>>(Wx0, Wx1, Wih, Wh0, Wh1, Wg,
                                bx0, bx1, bih, bh0, bh1, bg);
  pre<<<512, 512, 0, stream>>>(x, bufA);
  mega2<<<NRB + NGB, 512, 0, stream>>>(bufA, bufB, out, Whh, bhh);
}

// Round 6
// 1411.153 us; speedup vs baseline: 2.6005x; 1.0971x over previous
//
#include <hip/hip_runtime.h>
#include <cstddef>

// ---------------------------------------------------------------------------
// MT_RNN round 11: r10 intent, de-risked mechanics.
//   prep  : Wh0/Wh1/Wg (+biases) -> fp16 device globals, zero progress flags
//   gemm8 : steps (1)(2)(3) as three separate proven launches (~78us each)
//   mega2 : blocks 0-15 = rnn recurrence, blocks 16-255 = fused (5)+(6)+(7)
//           gated on rnn progress.
// CU dedication WITHOUT the 1024-thread early-exit trick (r10, untested
// barrier semantics, container failed twice): pad mega2's STATIC LDS to
// 84480 B so 2 blocks/CU is impossible (2x84480 > 163840). Static LDS >64KB
// is proven on gfx950 (8-phase template uses 128KB). 512-thr blocks, plain.
// Sync (r9-proven): phase B RELAXED spin + s_sleep + ONE acquire; rnn h_all
// stores non-temporal; publish every 32 steps via full drain + RELEASE.
// Buffers: bufA = zx [T,B,H] fp16; bufB = h_all [T,B,H] fp16 (ws >= 256MB).
// ---------------------------------------------------------------------------

typedef _Float16 halfx8 __attribute__((ext_vector_type(8)));
typedef _Float16 halfx4 __attribute__((ext_vector_type(4)));
typedef float    f32x4  __attribute__((ext_vector_type(4)));

#define T_LEN 1024
#define B_SZ  256
#define H_DIM 256
#define M_ROWS (T_LEN * B_SZ)   // 262144
#define MT     (M_ROWS / 32)    // 8192 tiles
#define NRB    16               // rnn blocks
#define NGB    240              // gemm blocks

__device__ _Float16 gWh0[256 * 256];
__device__ _Float16 gWh1[256 * 256];
__device__ _Float16 gWg[64 * 256];
__device__ float gBh0[256], gBh1[256], gBg[64];
__device__ unsigned gProg[NRB];   // rnn block b: h_all[0..prog) complete

__device__ __forceinline__ float fast_tanh(float x) {
  float e = __expf(2.0f * x);
  return 1.0f - 2.0f / (e + 1.0f);
}

// sorted alpha assignment over 256 units: 86 x 0.001, 85 x 0.01, 85 x 0.1
__device__ __forceinline__ float alpha_of(int j) {
  return (j < 86) ? 0.001f : ((j < 171) ? 0.01f : 0.1f);
}

// barrier with LDS-only drain: global loads/stores stay in flight across it
__device__ __forceinline__ void lds_barrier() {
  asm volatile("s_waitcnt lgkmcnt(0)\n\ts_barrier" ::: "memory");
}

// ---------------------------------------------------------------------------
// prep: zero flags, copy post-chain weights (fp32 -> fp16 globals) + biases.
// ---------------------------------------------------------------------------
__global__ void prep(const float* __restrict__ Wh0, const float* __restrict__ Wh1,
                     const float* __restrict__ Wg,  const float* __restrict__ bh0,
                     const float* __restrict__ bh1, const float* __restrict__ bg) {
  const int i = blockIdx.x * blockDim.x + threadIdx.x;  // 65536 threads
  if (i < NRB) gProg[i] = 0u;
  if (i < 16384) gWg[i] = (_Float16)Wg[i];
  if (i < 65536) {
    gWh0[i] = (_Float16)Wh0[i];
    gWh1[i] = (_Float16)Wh1[i];
  }
  if (i < 256) { gBh0[i] = bh0[i]; gBh1[i] = bh1[i]; }
  if (i < 64) gBg[i] = bg[i];
}

// ---------------------------------------------------------------------------
// fp16 MFMA GEMM, 8 waves, N=256, M-tile=32, grid-stride. W register-resident
// (fp32 source, converted at load). INF32: A fp32 (step 1), else fp16.
// MFMA 16x16x32 layouts (HW-verified):
//   A: A[m=lane&15][k=8*(lane>>4)+i]   B: B[k=8*(lane>>4)+i][n=lane&15]
//   D: col n=lane&15, row m=4*(lane>>4)+reg
// ---------------------------------------------------------------------------
template <int KCH, bool TANH, bool INF32>
__global__ __launch_bounds__(512, 2)
void gemm8(const void* __restrict__ Ap, const float* __restrict__ W,
           const float* __restrict__ bias, void* __restrict__ Cp, int mtiles) {
  constexpr int K  = KCH * 32;
  constexpr int KP = K + 8;
  __shared__ __attribute__((aligned(16))) _Float16 Ah[32][KP];

  const int tid  = threadIdx.x;
  const int lane = tid & 63;
  const int wave = tid >> 6;   // 0..7, owns 32 output columns
  const int l15  = lane & 15;
  const int quad = lane >> 4;
  const int jw   = wave * 32;

  halfx8 Bf[2][KCH];
  float  bcol[2];
  int    jj[2];
#pragma unroll
  for (int nt = 0; nt < 2; nt++) {
    jj[nt]   = jw + nt * 16 + l15;
    bcol[nt] = bias[jj[nt]];
#pragma unroll
    for (int ks = 0; ks < KCH; ks++) {
      const float* wp = W + (size_t)jj[nt] * K + ks * 32 + quad * 8;
      float4 w0 = *(const float4*)wp;
      float4 w1 = *(const float4*)(wp + 4);
      halfx8 f;
      f[0] = (_Float16)w0.x; f[1] = (_Float16)w0.y;
      f[2] = (_Float16)w0.z; f[3] = (_Float16)w0.w;
      f[4] = (_Float16)w1.x; f[5] = (_Float16)w1.y;
      f[6] = (_Float16)w1.z; f[7] = (_Float16)w1.w;
      Bf[nt][ks] = f;
    }
  }

  const int srow = tid >> 4;   // 0..31 (16 threads per row)
  const int sk4  = tid & 15;

  for (int bm = blockIdx.x; bm < mtiles; bm += gridDim.x) {
    if constexpr (INF32) {
      const float* A = (const float*)Ap + (size_t)bm * 32 * K;
      constexpr int SEG = K / 64;
      float4 tv[SEG];
#pragma unroll
      for (int s = 0; s < SEG; s++)
        tv[s] = *(const float4*)(A + (size_t)srow * K + (sk4 + s * 16) * 4);
#pragma unroll
      for (int s = 0; s < SEG; s++) {
        halfx4 h;
        h[0] = (_Float16)tv[s].x; h[1] = (_Float16)tv[s].y;
        h[2] = (_Float16)tv[s].z; h[3] = (_Float16)tv[s].w;
        *(halfx4*)&Ah[srow][(sk4 + s * 16) * 4] = h;
      }
    } else {
      const _Float16* A = (const _Float16*)Ap + (size_t)bm * 32 * K;
      constexpr int SEG = K / 128;
      halfx8 tv[SEG];
#pragma unroll
      for (int s = 0; s < SEG; s++)
        tv[s] = *(const halfx8*)(A + (size_t)srow * K + (sk4 + s * 16) * 8);
#pragma unroll
      for (int s = 0; s < SEG; s++)
        *(halfx8*)&Ah[srow][(sk4 + s * 16) * 8] = tv[s];
    }
    lds_barrier();

    f32x4 acc[2][2];
#pragma unroll
    for (int mi = 0; mi < 2; mi++)
#pragma unroll
      for (int nt = 0; nt < 2; nt++) acc[mi][nt] = (f32x4){0.f, 0.f, 0.f, 0.f};

#pragma unroll
    for (int ks = 0; ks < KCH; ks++)
#pragma unroll
      for (int mi = 0; mi < 2; mi++) {
        halfx8 a = *(const halfx8*)&Ah[mi * 16 + l15][ks * 32 + quad * 8];
#pragma unroll
        for (int nt = 0; nt < 2; nt++)
          acc[mi][nt] = __builtin_amdgcn_mfma_f32_16x16x32_f16(a, Bf[nt][ks], acc[mi][nt], 0, 0, 0);
      }

    _Float16* C = (_Float16*)Cp;
#pragma unroll
    for (int mi = 0; mi < 2; mi++)
#pragma unroll
      for (int nt = 0; nt < 2; nt++)
#pragma unroll
        for (int rg = 0; rg < 4; rg++) {
          const int rowg = bm * 32 + mi * 16 + quad * 4 + rg;
          float v = acc[mi][nt][rg] + bcol[nt];
          if (TANH) v = fast_tanh(v);
          C[(size_t)rowg * 256 + jj[nt]] = (_Float16)v;
        }
    lds_barrier();  // MFMA reads done before next tile's staging writes
  }
}

// ---------------------------------------------------------------------------
// Fused GEMM stage: Ch[32][264] = act(Ah @ W^T + b). 8 waves, 32 cols/wave.
// W fp16 [256][K] device globals (L2-hot).
// ---------------------------------------------------------------------------
template <int KCH, bool TANH>
__device__ __forceinline__ void stage_tile(const _Float16 (*__restrict__ Ah)[264],
                                           _Float16 (*__restrict__ Ch)[264],
                                           const _Float16* __restrict__ W,
                                           const float* __restrict__ bias,
                                           const int tid) {
  constexpr int K = KCH * 32;
  const int lane = tid & 63, wave = tid >> 6, l15 = lane & 15, quad = lane >> 4;
  const int jw = wave * 32;

  halfx8 Bf[2][KCH];
  float bcol[2];
  int jj[2];
#pragma unroll
  for (int nt = 0; nt < 2; nt++) {
    jj[nt] = jw + nt * 16 + l15;
    bcol[nt] = bias[jj[nt]];
#pragma unroll
    for (int ks = 0; ks < KCH; ks++)
      Bf[nt][ks] = *(const halfx8*)(W + (size_t)jj[nt] * K + ks * 32 + quad * 8);
  }

  f32x4 acc[2][2];
#pragma unroll
  for (int mi = 0; mi < 2; mi++)
#pragma unroll
    for (int nt = 0; nt < 2; nt++) acc[mi][nt] = (f32x4){0.f, 0.f, 0.f, 0.f};

#pragma unroll
  for (int ks = 0; ks < KCH; ks++)
#pragma unroll
    for (int mi = 0; mi < 2; mi++) {
      halfx8 a = *(const halfx8*)&Ah[mi * 16 + l15][ks * 32 + quad * 8];
#pragma unroll
      for (int nt = 0; nt < 2; nt++)
        acc[mi][nt] = __builtin_amdgcn_mfma_f32_16x16x32_f16(a, Bf[nt][ks], acc[mi][nt], 0, 0, 0);
    }

#pragma unroll
  for (int mi = 0; mi < 2; mi++)
#pragma unroll
    for (int nt = 0; nt < 2; nt++)
#pragma unroll
      for (int rg = 0; rg < 4; rg++) {
        float v = acc[mi][nt][rg] + bcol[nt];
        if (TANH) v = fast_tanh(v);
        Ch[mi * 16 + quad * 4 + rg][jj[nt]] = (_Float16)v;
      }
}

// Final projection tile: out[32,64] fp32 = Ah @ Wg^T + bg. Waves 0-3 only.
__device__ __forceinline__ void stage_out(const _Float16 (*__restrict__ Ah)[264],
                                          float* __restrict__ C,
                                          const _Float16* __restrict__ W,
                                          const float* __restrict__ bias,
                                          const int tid) {
  const int lane = tid & 63, wave = tid >> 6, l15 = lane & 15, quad = lane >> 4;
  if (wave < 4) {
    const int jcol = wave * 16 + l15;
    halfx8 Bf[8];
#pragma unroll
    for (int ks = 0; ks < 8; ks++)
      Bf[ks] = *(const halfx8*)(W + (size_t)jcol * 256 + ks * 32 + quad * 8);
    const float bc = bias[jcol];
    f32x4 acc[2];
#pragma unroll
    for (int mi = 0; mi < 2; mi++) acc[mi] = (f32x4){0.f, 0.f, 0.f, 0.f};
#pragma unroll
    for (int ks = 0; ks < 8; ks++)
#pragma unroll
      for (int mi = 0; mi < 2; mi++) {
        halfx8 a = *(const halfx8*)&Ah[mi * 16 + l15][ks * 32 + quad * 8];
        acc[mi] = __builtin_amdgcn_mfma_f32_16x16x32_f16(a, Bf[ks], acc[mi], 0, 0, 0);
      }
#pragma unroll
    for (int mi = 0; mi < 2; mi++)
#pragma unroll
      for (int rg = 0; rg < 4; rg++)
        C[(size_t)(mi * 16 + quad * 4 + rg) * 64 + jcol] = acc[mi][rg] + bc;
  }
}

// ---------------------------------------------------------------------------
// rnn block body: 8 waves (2/SIMD), swapped operands (Whh register-resident
// A, h as B from LDS). h_all stores NON-TEMPORAL; progress published every
// 32 steps: full-drain barrier + agent-scope RELEASE store by tid 0.
// ---------------------------------------------------------------------------
__device__ void rnn_block(const _Float16* __restrict__ zx,
                          _Float16* __restrict__ h_all,
                          const float* __restrict__ Whh,
                          const float* __restrict__ bhh_p,
                          _Float16 (*__restrict__ lds)[264],
                          const int bid) {
  _Float16(*hB)[16][264] = reinterpret_cast<_Float16(*)[16][264]>(&lds[0][0]);

  const int tid  = threadIdx.x;
  const int lane = tid & 63;
  const int wave = tid >> 6;   // 0..7, owns 32 h-columns
  const int l15  = lane & 15;
  const int quad = lane >> 4;
  const int r0   = bid * 16;
  const int jb   = wave * 32;

  halfx8 Af[2][8];
#pragma unroll
  for (int mt = 0; mt < 2; mt++) {
    const int j = jb + mt * 16 + l15;
#pragma unroll
    for (int ks = 0; ks < 8; ks++) {
      const float* wp = Whh + (size_t)j * H_DIM + ks * 32 + quad * 8;
      float4 w0 = *(const float4*)wp;
      float4 w1 = *(const float4*)(wp + 4);
      halfx8 f;
      f[0] = (_Float16)w0.x; f[1] = (_Float16)w0.y;
      f[2] = (_Float16)w0.z; f[3] = (_Float16)w0.w;
      f[4] = (_Float16)w1.x; f[5] = (_Float16)w1.y;
      f[6] = (_Float16)w1.z; f[7] = (_Float16)w1.w;
      Af[mt][ks] = f;
    }
  }

  float bj[2][4], aj[2][4], oma[2][4];
#pragma unroll
  for (int mt = 0; mt < 2; mt++)
#pragma unroll
    for (int rg = 0; rg < 4; rg++) {
      const int j = jb + mt * 16 + quad * 4 + rg;
      bj[mt][rg]  = bhh_p[j];
      aj[mt][rg]  = alpha_of(j);
      oma[mt][rg] = 1.0f - aj[mt][rg];
    }

  for (int i = tid; i < 16 * 264; i += 512) (&hB[0][0][0])[i] = (_Float16)0.0f;
  __syncthreads();

  const _Float16* rdp[2] = {&hB[0][l15][quad * 8], &hB[1][l15][quad * 8]};
  _Float16*       wrp[2] = {&hB[1][l15][jb + quad * 4], &hB[0][l15][jb + quad * 4]};

  constexpr int STRIDE = B_SZ * H_DIM;
  const _Float16* zp = zx    + (size_t)(r0 + l15) * H_DIM + jb + quad * 4;
  _Float16*       hp = h_all + (size_t)(r0 + l15) * H_DIM + jb + quad * 4;

  float  zc[2][4];
  halfx4 zA[2];
  {
#pragma unroll
    for (int mt = 0; mt < 2; mt++) {
      halfx4 z0 = *(const halfx4*)(zp + mt * 16);
      zA[mt]    = *(const halfx4*)(zp + mt * 16 + STRIDE);
#pragma unroll
      for (int rg = 0; rg < 4; rg++) zc[mt][rg] = (float)z0[rg];
    }
    zp += 2 * (size_t)STRIDE;
  }

  float  hreg[2][4];
  halfx4 hh4[2];
#pragma unroll
  for (int mt = 0; mt < 2; mt++)
#pragma unroll
    for (int rg = 0; rg < 4; rg++) { hreg[mt][rg] = 0.0f; hh4[mt][rg] = (_Float16)0.0f; }

  auto step = [&](int p, bool pub, unsigned pval) {
    halfx4 znew[2];
#pragma unroll
    for (int mt = 0; mt < 2; mt++) znew[mt] = *(const halfx4*)(zp + mt * 16);
    zp += STRIDE;

    const _Float16* rd = rdp[p];
    halfx8 hb[8];
#pragma unroll
    for (int ks = 0; ks < 8; ks++) hb[ks] = *(const halfx8*)(rd + ks * 32);

    f32x4 acc[2];
#pragma unroll
    for (int mt = 0; mt < 2; mt++) acc[mt] = (f32x4){0.f, 0.f, 0.f, 0.f};
#pragma unroll
    for (int ks = 0; ks < 8; ks++)
#pragma unroll
      for (int mt = 0; mt < 2; mt++)
        acc[mt] = __builtin_amdgcn_mfma_f32_16x16x32_f16(Af[mt][ks], hb[ks], acc[mt], 0, 0, 0);

    _Float16* wr = wrp[p];
#pragma unroll
    for (int mt = 0; mt < 2; mt++) {
      halfx4 hnew;
#pragma unroll
      for (int rg = 0; rg < 4; rg++) {
        float hr = fast_tanh(zc[mt][rg] + acc[mt][rg] + bj[mt][rg]);
        float hn = oma[mt][rg] * hreg[mt][rg] + aj[mt][rg] * hr;
        hreg[mt][rg] = hn;
        hnew[rg] = (_Float16)hn;
      }
      // h_all[t] = pre-update h_t, non-temporal (no dirty L2 line)
      __builtin_nontemporal_store(
          __builtin_bit_cast(unsigned long long, hh4[mt]),
          (unsigned long long*)(hp + mt * 16));
      hh4[mt] = hnew;
      *(halfx4*)(wr + mt * 16) = hnew;      // next step's B operand
    }
    hp += STRIDE;

    if (pub) {
      // all waves' h_all stores complete, then release progress
      asm volatile("s_waitcnt vmcnt(0) lgkmcnt(0)\n\ts_barrier" ::: "memory");
      if (tid == 0)
        __hip_atomic_store(&gProg[bid], pval, __ATOMIC_RELEASE,
                           __HIP_MEMORY_SCOPE_AGENT);
    } else {
      lds_barrier();
    }

#pragma unroll
    for (int mt = 0; mt < 2; mt++) {
#pragma unroll
      for (int rg = 0; rg < 4; rg++) zc[mt][rg] = (float)zA[mt][rg];
      zA[mt] = znew[mt];
    }
  };

  for (int it = 0; it < T_LEN / 2; ++it) {
    const int t0 = 2 * it;
    step(0, false, 0u);
    step(1, (it & 15) == 15, (unsigned)(t0 + 2));  // every 32 steps; final=1024
  }
}

// ---------------------------------------------------------------------------
// mega2: rnn (blocks 0-15) + fused post-chain (blocks 16-255).
// 512 threads; LDS padded to 84480 B so 2 blocks/CU is impossible
// (2 x 84480 = 168960 > 163840) -> every block gets a dedicated CU.
// Only lds[0] and lds[1] are used; [2..4] are occupancy ballast.
// ---------------------------------------------------------------------------
__global__ __launch_bounds__(512, 1)
void mega2(const _Float16* __restrict__ zx, _Float16* __restrict__ h_all,
           float* __restrict__ out, const float* __restrict__ Whh,
           const float* __restrict__ bhh_p) {
  __shared__ __attribute__((aligned(16))) _Float16 lds[5][32][264];
  const int tid = threadIdx.x;

  if (blockIdx.x < NRB) {
    rnn_block(zx, h_all, Whh, bhh_p, lds[0], blockIdx.x);
    return;
  }

  const int g = blockIdx.x - NRB;  // 0..NGB-1
  _Float16(*Ah)[264] = lds[0];
  _Float16(*Bh)[264] = lds[1];

  for (int bm = g; bm < MT; bm += NGB) {
    const int t = bm >> 3, b2 = bm & 7;
    const unsigned need = (unsigned)(t + 1);
    if (tid == 0) {
      // RELAXED spin (no cache invalidation), ONE acquire after success
      while (__hip_atomic_load(&gProg[2 * b2], __ATOMIC_RELAXED,
                               __HIP_MEMORY_SCOPE_AGENT) < need ||
             __hip_atomic_load(&gProg[2 * b2 + 1], __ATOMIC_RELAXED,
                               __HIP_MEMORY_SCOPE_AGENT) < need)
        __builtin_amdgcn_s_sleep(16);
      unsigned v = __hip_atomic_load(&gProg[2 * b2], __ATOMIC_ACQUIRE,
                                     __HIP_MEMORY_SCOPE_AGENT);
      asm volatile("" ::"v"(v));
    }
    __syncthreads();
    {  // stage h tile (32 x 256 fp16)
      const int srow = tid >> 4, sk4 = tid & 15;
      const _Float16* hsrc = h_all + (size_t)bm * 32 * 256 + (size_t)srow * 256 + sk4 * 16;
      halfx8 t0 = *(const halfx8*)hsrc;
      halfx8 t1 = *(const halfx8*)(hsrc + 8);
      *(halfx8*)&Ah[srow][sk4 * 16] = t0;
      *(halfx8*)&Ah[srow][sk4 * 16 + 8] = t1;
    }
    lds_barrier();
    stage_tile<8, true>(Ah, Bh, gWh0, gBh0, tid);
    lds_barrier();
    stage_tile<8, true>(Bh, Ah, gWh1, gBh1, tid);
    lds_barrier();
    stage_out(Ah, out + (size_t)bm * 32 * 64, gWg, gBg, tid);
    lds_barrier();  // stage_out's Ah reads done before next tile's staging
  }
}

// ---------------------------------------------------------------------------
extern "C" void kernel_launch(void* const* d_in, const int* in_sizes, int n_in,
                              void* d_out, int out_size, void* d_ws, size_t ws_size,
                              hipStream_t stream) {
  const float* x   = (const float*)d_in[0];
  const float* Wx0 = (const float*)d_in[1];
  const float* bx0 = (const float*)d_in[2];
  const float* Wx1 = (const float*)d_in[3];
  const float* bx1 = (const float*)d_in[4];
  const float* Wih = (const float*)d_in[5];
  const float* Whh = (const float*)d_in[6];
  const float* bih = (const float*)d_in[7];
  const float* bhh = (const float*)d_in[8];
  const float* Wh0 = (const float*)d_in[9];
  const float* bh0 = (const float*)d_in[10];
  const float* Wh1 = (const float*)d_in[11];
  const float* bh1 = (const float*)d_in[12];
  const float* Wg  = (const float*)d_in[13];
  const float* bg  = (const float*)d_in[14];
  float* out = (float*)d_out;

  // two fp16 ping-pong halves, 128 MiB each (ws >= 256 MiB)
  _Float16* bufA = (_Float16*)d_ws;                // zx    [T,B,H]
  _Float16* bufB = bufA + (size_t)M_ROWS * 256;    // h_all [T,B,H]

  prep<<<256, 256, 0, stream>>>(Wh0, Wh1, Wg, bh0, bh1, bg);
  // 1) bufA = tanh(x Wx0^T + bx0)            fp32 -> fp16
  gemm8<2, true, true><<<512, 512, 0, stream>>>(x, Wx0, bx0, bufA, MT);
  // 2) bufB = tanh(bufA Wx1^T + bx1)
  gemm8<8, true, false><<<512, 512, 0, stream>>>(bufA, Wx1, bx1, bufB, MT);
  // 3) bufA = bufB Wih^T + bih               zx [T,B,H]
  gemm8<8, false, false><<<512, 512, 0, stream>>>(bufB, Wih, bih, bufA, MT);
  // 4+5+6+7) rnn (dedicated CUs by LDS ballast) overlapped with post-chain
  mega2<<<NRB + NGB, 512, 0, stream>>>(bufA, bufB, out, Whh, bhh);
}